// Round 9
// baseline (63.691 us; speedup 1.0000x reference)
//
#include <hip/hip_runtime.h>
#include <float.h>

#define BT 8
#define NV 10000
#define NB 16384
#define NS 4096
#define NPTS (BT * NS)          // 32768 points
#define PPT 16                  // points per thread (8 packed pairs)
#define PB 8                    // point blocks = batches (4096 pts each)
#define VCH 125                 // vertex chunks
#define CH 80                   // verts per chunk: 125*80 = 10000 exact

typedef float v2f __attribute__((ext_vector_type(2)));

// VOP3P packed fp32 FMA with op_sel broadcast (all verified passing in r8).
__device__ __forceinline__ v2f pk_fma_zw(v2f a, v2f q) {   // a*(q.z,q.z)+(q.w,q.w)
    v2f d;
    asm("v_pk_fma_f32 %0, %1, %2, %2 op_sel:[0,0,1] op_sel_hi:[1,0,1]"
        : "=v"(d) : "v"(a), "v"(q));
    return d;
}
__device__ __forceinline__ v2f pk_fma_hi(v2f a, v2f q, v2f c) {  // a*(q.hi,q.hi)+c
    v2f d;
    asm("v_pk_fma_f32 %0, %1, %2, %3 op_sel:[0,1,0] op_sel_hi:[1,1,1]"
        : "=v"(d) : "v"(a), "v"(q), "v"(c));
    return d;
}
__device__ __forceinline__ v2f pk_fma_lo(v2f a, v2f q, v2f c) {  // a*(q.lo,q.lo)+c
    v2f d;
    asm("v_pk_fma_f32 %0, %1, %2, %3 op_sel:[0,0,0] op_sel_hi:[1,0,1]"
        : "=v"(d) : "v"(a), "v"(q), "v"(c));
    return d;
}
__device__ __forceinline__ float min3f(float a, float b, float c) {
    float d;
    asm("v_min3_f32 %0, %1, %2, %3" : "=v"(d) : "v"(a), "v"(b), "v"(c));
    return d;
}

// Prep: gather each point ONCE (kills the 125x redundant random gather).
__global__ void prep(const float4* __restrict__ bds4, const int* __restrict__ idx,
                     float4* __restrict__ bg) {
    int pt = blockIdx.x * 256 + threadIdx.x;          // 128 blocks
    int b = pt >> 12, s = pt & (NS - 1);
    bg[pt] = bds4[(size_t)b * NB + idx[s]];           // (x,y,z,mask)
}

// Stage 1: grid = PB*VCH = 1000 blocks. Block (b,c): whole batch b (16 pts/thr,
// coalesced from bg) vs verts [c*80,+80) staged in LDS as (-2x,-2y,-2z,|v|^2).
__global__ void __launch_bounds__(256, 4)
stage1(const float* __restrict__ verts, const float4* __restrict__ bg,
       float* __restrict__ pmin) {
    __shared__ float4 sv[CH];
    const int tid = threadIdx.x;
    const int b   = blockIdx.x & (PB - 1);
    const int c   = blockIdx.x >> 3;
    const int v0  = c * CH;

    if (tid < CH) {
        const float* vp = verts + (size_t)(b * NV + v0 + tid) * 3;
        float x = vp[0], y = vp[1], z = vp[2];
        sv[tid] = make_float4(-2.0f * x, -2.0f * y, -2.0f * z,
                              x * x + y * y + z * z);
    }

    v2f bx[8], by[8], bz[8];
    float mA[8], mB[8];
#pragma unroll
    for (int pp = 0; pp < 8; ++pp) {
        int pt0 = b * NS + tid + pp * 512;            // coalesced
        float4 q0 = bg[pt0];
        float4 q1 = bg[pt0 + 256];
        bx[pp] = (v2f){q0.x, q1.x};
        by[pp] = (v2f){q0.y, q1.y};
        bz[pp] = (v2f){q0.z, q1.z};
        mA[pp] = FLT_MAX; mB[pp] = FLT_MAX;
    }
    __syncthreads();

    for (int v = 0; v < CH; v += 2) {
        float4 qa = sv[v], qb = sv[v + 1];
        v2f qa01 = {qa.x, qa.y}, qa23 = {qa.z, qa.w};
        v2f qb01 = {qb.x, qb.y}, qb23 = {qb.z, qb.w};
#pragma unroll
        for (int pp = 0; pp < 8; ++pp) {
            v2f t0 = pk_fma_zw(bz[pp], qa23);
            t0 = pk_fma_hi(by[pp], qa01, t0);
            t0 = pk_fma_lo(bx[pp], qa01, t0);
            v2f t1 = pk_fma_zw(bz[pp], qb23);
            t1 = pk_fma_hi(by[pp], qb01, t1);
            t1 = pk_fma_lo(bx[pp], qb01, t1);
            mA[pp] = min3f(mA[pp], t0.x, t1.x);
            mB[pp] = min3f(mB[pp], t0.y, t1.y);
        }
    }

#pragma unroll
    for (int pp = 0; pp < 8; ++pp) {
        int pt0 = b * NS + tid + pp * 512;
        pmin[(size_t)c * NPTS + pt0]       = mA[pp];
        pmin[(size_t)c * NPTS + pt0 + 256] = mB[pp];
    }
}

// Stage 2: combine chunk mins, add sq_b, mask, per-block sum (bg coalesced).
__global__ void stage2(const float* __restrict__ pmin, const float4* __restrict__ bg,
                       float* __restrict__ bsum) {
    int pt = blockIdx.x * 256 + threadIdx.x;
    float4 bp = bg[pt];
    float md = FLT_MAX;
#pragma unroll 5
    for (int c = 0; c < VCH; ++c)
        md = fminf(md, pmin[(size_t)c * NPTS + pt]);
    float sqb = bp.x * bp.x + bp.y * bp.y + bp.z * bp.z;
    float val = (md + sqb) * bp.w * (1.0f / (float)NPTS);
    for (int o = 32; o > 0; o >>= 1) val += __shfl_down(val, o, 64);
    __shared__ float red[4];
    if ((threadIdx.x & 63) == 0) red[threadIdx.x >> 6] = val;
    __syncthreads();
    if (threadIdx.x == 0) bsum[blockIdx.x] = red[0] + red[1] + red[2] + red[3];
}

// Stage 3: final sum of 128 block partials -> scalar
__global__ void stage3(const float* __restrict__ bsum, float* __restrict__ out) {
    float v = bsum[threadIdx.x];  // 128 threads
    for (int o = 32; o > 0; o >>= 1) v += __shfl_down(v, o, 64);
    __shared__ float r[2];
    if ((threadIdx.x & 63) == 0) r[threadIdx.x >> 6] = v;
    __syncthreads();
    if (threadIdx.x == 0) out[0] = r[0] + r[1];
}

extern "C" void kernel_launch(void* const* d_in, const int* in_sizes, int n_in,
                              void* d_out, int out_size, void* d_ws, size_t ws_size,
                              hipStream_t stream) {
    const float*  verts = (const float*)d_in[0];
    const float4* bds4  = (const float4*)d_in[1];  // (BT, NB, 4) rows
    const int*    idx   = (const int*)d_in[3];     // int32
    float* out = (float*)d_out;

    char* ws = (char*)d_ws;
    float4* bg  = (float4*)ws;                                  // 512 KB
    float* pmin = (float*)(ws + (size_t)NPTS * sizeof(float4)); // 16 MB
    float* bsum = (float*)(ws + (size_t)NPTS * sizeof(float4)
                              + (size_t)VCH * NPTS * sizeof(float));

    prep<<<NPTS / 256, 256, 0, stream>>>(bds4, idx, bg);
    stage1<<<PB * VCH, 256, 0, stream>>>(verts, bg, pmin);
    stage2<<<NPTS / 256, 256, 0, stream>>>(pmin, bg, bsum);
    stage3<<<1, 128, 0, stream>>>(bsum, out);
}

// Round 10
// 48.297 us; speedup vs baseline: 1.3187x; 1.3187x over previous
//
#include <hip/hip_runtime.h>
#include <float.h>

#define BT 8
#define NV 10000
#define NB 16384
#define NS 4096
#define NPTS (BT * NS)          // 32768 points
#define PB 16                   // point blocks (2048 pts each, 8/thread)
#define VCH 64                  // vertex chunks
#define CH 157                  // 64*157 = 10048 >= NV (last chunk tn=109)
#define CHPAD 160               // CH rounded up to multiple of 4

__device__ __forceinline__ float min3f(float a, float b, float c) {
    float d;
    asm("v_min3_f32 %0, %1, %2, %3" : "=v"(d) : "v"(a), "v"(b), "v"(c));
    return d;
}
// order-preserving float <-> uint (total order matches float compare)
__device__ __forceinline__ unsigned enc(float f) {
    unsigned u = __float_as_uint(f);
    return (u & 0x80000000u) ? ~u : (u | 0x80000000u);
}
__device__ __forceinline__ float dec(unsigned u) {
    unsigned v = (u & 0x80000000u) ? (u & 0x7FFFFFFFu) : ~u;
    return __uint_as_float(v);
}

// Prep: gather each point once; init pmin to +inf encoding.
__global__ void prep(const float4* __restrict__ bds4, const int* __restrict__ idx,
                     float4* __restrict__ bg, unsigned* __restrict__ pmin) {
    int pt = blockIdx.x * 256 + threadIdx.x;      // 128 blocks
    int b = pt >> 12, s = pt & (NS - 1);
    bg[pt] = bds4[(size_t)b * NB + idx[s]];       // (x,y,z,mask)
    pmin[pt] = 0xFFFFFFFFu;
}

// Main: grid = PB*VCH = 1024 blocks (4/CU). Block (pb,c): 2048 points
// (8/thread, coalesced bg) vs verts [c*157,+157) staged in LDS as
// (-2x,-2y,-2z,|v|^2). Cross-chunk min via atomicMin on encoded uint (L2).
__global__ void __launch_bounds__(256, 4)
mainker(const float* __restrict__ verts, const float4* __restrict__ bg,
        unsigned* __restrict__ pmin) {
    __shared__ float4 sv[CHPAD];
    const int tid = threadIdx.x;
    const int pb  = blockIdx.x & (PB - 1);
    const int c   = blockIdx.x >> 4;
    const int b   = pb >> 1;                 // 2 point-blocks per batch
    const int p0  = pb * 2048;
    const int v0  = c * CH;
    const int vend = (v0 + CH < NV) ? (v0 + CH) : NV;
    const int tn  = vend - v0;
    const int tn4 = (tn + 3) & ~3;

    if (tid < tn4) {
        float4 q;
        if (tid < tn) {
            const float* vp = verts + (size_t)(b * NV + v0 + tid) * 3;
            float x = vp[0], y = vp[1], z = vp[2];
            q = make_float4(-2.0f * x, -2.0f * y, -2.0f * z,
                            x * x + y * y + z * z);
        } else {
            q = make_float4(0.0f, 0.0f, 0.0f, 3.4e38f);  // sentinel never wins
        }
        sv[tid] = q;
    }

    float bx[8], by[8], bz[8], m[8];
#pragma unroll
    for (int k = 0; k < 8; ++k) {
        float4 bp = bg[p0 + tid + k * 256];  // coalesced
        bx[k] = bp.x; by[k] = bp.y; bz[k] = bp.z;
        m[k] = FLT_MAX;
    }
    __syncthreads();

    for (int v = 0; v < tn4; v += 4) {
        float4 q0 = sv[v], q1 = sv[v + 1], q2 = sv[v + 2], q3 = sv[v + 3];
#pragma unroll
        for (int k = 0; k < 8; ++k) {
            float t0 = fmaf(bx[k], q0.x, fmaf(by[k], q0.y, fmaf(bz[k], q0.z, q0.w)));
            float t1 = fmaf(bx[k], q1.x, fmaf(by[k], q1.y, fmaf(bz[k], q1.z, q1.w)));
            float t2 = fmaf(bx[k], q2.x, fmaf(by[k], q2.y, fmaf(bz[k], q2.z, q2.w)));
            float t3 = fmaf(bx[k], q3.x, fmaf(by[k], q3.y, fmaf(bz[k], q3.z, q3.w)));
            m[k] = min3f(m[k], t0, t1);
            m[k] = min3f(m[k], t2, t3);
        }
    }

#pragma unroll
    for (int k = 0; k < 8; ++k)
        atomicMin(&pmin[p0 + tid + k * 256], enc(m[k]));
}

// Finalize: one block, exact order-independent fixed-point sum (deterministic).
__global__ void __launch_bounds__(1024)
finalize(const unsigned* __restrict__ pmin, const float4* __restrict__ bg,
         float* __restrict__ out) {
    __shared__ long long sl[1024];
    const int tid = threadIdx.x;
    long long acc = 0;
    for (int i = tid; i < NPTS; i += 1024) {
        float md = dec(pmin[i]);
        float4 bp = bg[i];
        float sqb = bp.x * bp.x + bp.y * bp.y + bp.z * bp.z;
        float val = (md + sqb) * bp.w;           // mask is 0.0 or 1.0
        acc += llrint((double)val * 1099511627776.0);   // * 2^40
    }
    sl[tid] = acc;
    __syncthreads();
    for (int o = 512; o > 0; o >>= 1) {
        if (tid < o) sl[tid] += sl[tid + o];
        __syncthreads();
    }
    if (tid == 0)
        out[0] = (float)((double)sl[0] / 1099511627776.0 / (double)NPTS);
}

extern "C" void kernel_launch(void* const* d_in, const int* in_sizes, int n_in,
                              void* d_out, int out_size, void* d_ws, size_t ws_size,
                              hipStream_t stream) {
    const float*  verts = (const float*)d_in[0];
    const float4* bds4  = (const float4*)d_in[1];  // (BT, NB, 4) rows
    const int*    idx   = (const int*)d_in[3];     // int32
    float* out = (float*)d_out;

    char* ws = (char*)d_ws;
    float4*   bg   = (float4*)ws;                               // 512 KB
    unsigned* pmin = (unsigned*)(ws + (size_t)NPTS * sizeof(float4));  // 128 KB
    // total ws use: 640 KB

    prep<<<NPTS / 256, 256, 0, stream>>>(bds4, idx, bg, pmin);
    mainker<<<PB * VCH, 256, 0, stream>>>(verts, bg, pmin);
    finalize<<<1, 1024, 0, stream>>>(pmin, bg, out);
}